// Round 4
// baseline (109.658 us; speedup 1.0000x reference)
//
#include <hip/hip_runtime.h>
#include <stdint.h>

#define NROWS 4096
#define DIM   512
#define EPS_COS 1e-8f
#define EPS_W   1e-6f
#define BT     256                 // output tile: BT x BT
#define NTILE  (NROWS / BT)        // 16
#define NKSTEP (DIM / 64)          // 8

typedef unsigned short ushort_t;
typedef __attribute__((ext_vector_type(8))) short   short8;
typedef __attribute__((ext_vector_type(8))) unsigned short ushort8;
typedef __attribute__((ext_vector_type(4))) float   floatx4;

// ---------- helpers ----------
__device__ inline ushort_t f2bf(float x) {            // RNE float->bf16
    unsigned u = __float_as_uint(x);
    unsigned r = (u + 0x7FFFu + ((u >> 16) & 1u)) >> 16;
    return (ushort_t)r;
}
__device__ inline float bf2f(ushort_t u) {
    return __uint_as_float(((unsigned)u) << 16);
}
// monotone float<->uint mapping for atomicMin/Max on floats
__device__ inline unsigned fmap(float f) {
    unsigned u = __float_as_uint(f);
    return (u & 0x80000000u) ? ~u : (u | 0x80000000u);
}
__device__ inline float funmap(unsigned u) {
    return __uint_as_float((u & 0x80000000u) ? (u & 0x7fffffffu) : ~u);
}

__device__ inline void gload_lds16(const void* g, void* l) {
    auto* gp = reinterpret_cast<const __attribute__((address_space(1))) unsigned int*>(
        reinterpret_cast<uintptr_t>(g));
    auto* lp = reinterpret_cast<__attribute__((address_space(3))) unsigned int*>(
        reinterpret_cast<uintptr_t>(l));
    __builtin_amdgcn_global_load_lds(gp, lp, 16, 0, 0);
}

// stage a 256x64 bf16 tile with 8 waves (512 threads): 4 gload_lds per wave.
// linear LDS dest + inverse-swizzled global source.
// LDS[r][c_phys] holds logical chunk c_phys ^ (r&7)  (chunk = 16B = 8 bf16)
__device__ inline void stage_tile(const ushort_t* __restrict__ gbase, // tile row0 + k0 applied
                                  ushort_t* lds, int wave, int lane) {
#pragma unroll
    for (int q = 0; q < 4; q++) {
        int row0 = wave * 32 + q * 8;                 // 8 waves cover 256 rows
        int lrow = row0 + (lane >> 3);
        int src_chunk = (lane & 7) ^ (lane >> 3);     // (lane&7) ^ (lrow&7)
        const ushort_t* g = gbase + (size_t)lrow * DIM + src_chunk * 8;
        gload_lds16(g, lds + row0 * 64);              // wave-uniform base; HW adds lane*16
    }
}

// fragment read: lane l -> row = frag_row*16 + (l&15), logical chunk = kk*4 + (l>>4),
// phys chunk = logical ^ (row&7)
__device__ inline short8 read_frag(const ushort_t* tile, int frag_row, int kk, int lane) {
    int r = frag_row * 16 + (lane & 15);
    int c = (kk * 4 + (lane >> 4)) ^ (lane & 7);
    return *reinterpret_cast<const short8*>(tile + r * 64 + c * 8);
}

// ---------- kernel 1: convert + norms + init ----------
__global__ __launch_bounds__(256) void prep_kernel(
    const float* __restrict__ img, const float* __restrict__ txt,
    ushort_t* __restrict__ Ibf, ushort_t* __restrict__ Tbf,
    float* __restrict__ img_norm, float* __restrict__ txt_norm,
    unsigned* __restrict__ mn_u, unsigned* __restrict__ mx_u) {
    const int wave = threadIdx.x >> 6, lane = threadIdx.x & 63;
    const int row = blockIdx.x * 4 + wave;
    const int col0 = lane * 8;
    {
        const float4* p = reinterpret_cast<const float4*>(img + (size_t)row * DIM + col0);
        float4 a = p[0], b = p[1];
        float ss = a.x*a.x + a.y*a.y + a.z*a.z + a.w*a.w
                 + b.x*b.x + b.y*b.y + b.z*b.z + b.w*b.w;
        ushort8 o;
        o[0]=f2bf(a.x); o[1]=f2bf(a.y); o[2]=f2bf(a.z); o[3]=f2bf(a.w);
        o[4]=f2bf(b.x); o[5]=f2bf(b.y); o[6]=f2bf(b.z); o[7]=f2bf(b.w);
        *reinterpret_cast<ushort8*>(Ibf + (size_t)row * DIM + col0) = o;
#pragma unroll
        for (int s = 1; s < 64; s <<= 1) ss += __shfl_xor(ss, s);
        if (lane == 0) img_norm[row] = sqrtf(ss);
    }
    {
        const float4* p = reinterpret_cast<const float4*>(txt + (size_t)row * DIM + col0);
        float4 a = p[0], b = p[1];
        float ss = a.x*a.x + a.y*a.y + a.z*a.z + a.w*a.w
                 + b.x*b.x + b.y*b.y + b.z*b.z + b.w*b.w;
        ushort8 o;
        o[0]=f2bf(a.x); o[1]=f2bf(a.y); o[2]=f2bf(a.z); o[3]=f2bf(a.w);
        o[4]=f2bf(b.x); o[5]=f2bf(b.y); o[6]=f2bf(b.z); o[7]=f2bf(b.w);
        *reinterpret_cast<ushort8*>(Tbf + (size_t)row * DIM + col0) = o;
#pragma unroll
        for (int s = 1; s < 64; s <<= 1) ss += __shfl_xor(ss, s);
        if (lane == 0) txt_norm[row] = sqrtf(ss);
    }
    if (lane == 0) { mn_u[row] = 0xFFFFFFFFu; mx_u[row] = 0u; }
}

// ---------- kernel 2: T.T^T -> row min/max atomics + packed bf16 sim store ----------
// Counted-vmcnt pipeline (T4): per K-step issue next-tile stage, then
// s_waitcnt vmcnt(8) (own 8 staging loads for CURRENT buf landed) -> s_barrier.
// Never drains vmcnt to 0 mid-loop. 8 waves, per-wave 128x64 output.
__global__ __launch_bounds__(512, 2) void phase1_kernel(
    const ushort_t* __restrict__ Tbf,
    unsigned* __restrict__ mn_u, unsigned* __restrict__ mx_u,
    ushort_t* __restrict__ simbuf) {
    __shared__ __align__(16) ushort_t Ta[2][BT * 64];   // 64 KB
    __shared__ __align__(16) ushort_t Tb[2][BT * 64];   // 64 KB
    const int tile_j = blockIdx.x, tile_i = blockIdx.y;
    const int tid = threadIdx.x;
    const int wave = tid >> 6, lane = tid & 63;
    const int wr = wave >> 2, wc = wave & 3;
    const ushort_t* gA = Tbf + (size_t)(tile_i * BT) * DIM;
    const ushort_t* gB = Tbf + (size_t)(tile_j * BT) * DIM;

    floatx4 acc[8][4];
#pragma unroll
    for (int m = 0; m < 8; m++)
#pragma unroll
        for (int n = 0; n < 4; n++) acc[m][n] = (floatx4){0.f, 0.f, 0.f, 0.f};

    stage_tile(gA, Ta[0], wave, lane);
    stage_tile(gB, Tb[0], wave, lane);
#pragma unroll
    for (int t = 0; t < NKSTEP; t++) {
        if (t + 1 < NKSTEP) {                          // prefetch next K-tile first
            stage_tile(gA + (t + 1) * 64, Ta[(t + 1) & 1], wave, lane);
            stage_tile(gB + (t + 1) * 64, Tb[(t + 1) & 1], wave, lane);
            asm volatile("s_waitcnt vmcnt(8)" ::: "memory");
        } else {
            asm volatile("s_waitcnt vmcnt(0)" ::: "memory");
        }
        __builtin_amdgcn_sched_barrier(0);
        __builtin_amdgcn_s_barrier();
#pragma unroll
        for (int kk = 0; kk < 2; kk++) {
            short8 a[8], b[4];
#pragma unroll
            for (int m = 0; m < 8; m++) a[m] = read_frag(Ta[t & 1], wr * 8 + m, kk, lane);
#pragma unroll
            for (int n = 0; n < 4; n++) b[n] = read_frag(Tb[t & 1], wc * 4 + n, kk, lane);
#pragma unroll
            for (int m = 0; m < 8; m++)
#pragma unroll
                for (int n = 0; n < 4; n++)
                    acc[m][n] = __builtin_amdgcn_mfma_f32_16x16x32_bf16(a[m], b[n], acc[m][n], 0, 0, 0);
        }
        __builtin_amdgcn_sched_barrier(0);
        __builtin_amdgcn_s_barrier();
    }

    // per-row min/max (fp32-exact); rows = tile_i*256 + wr*128 + m*16 + (l>>4)*4 + reg
#pragma unroll
    for (int m = 0; m < 8; m++) {
#pragma unroll
        for (int reg = 0; reg < 4; reg++) {
            float vmin = acc[m][0][reg], vmax = acc[m][0][reg];
#pragma unroll
            for (int n = 1; n < 4; n++) {
                vmin = fminf(vmin, acc[m][n][reg]);
                vmax = fmaxf(vmax, acc[m][n][reg]);
            }
#pragma unroll
            for (int s = 1; s < 16; s <<= 1) {
                vmin = fminf(vmin, __shfl_xor(vmin, s));
                vmax = fmaxf(vmax, __shfl_xor(vmax, s));
            }
            if ((lane & 15) == 0) {
                int row_g = tile_i * BT + wr * 128 + m * 16 + (lane >> 4) * 4 + reg;
                atomicMin(&mn_u[row_g], fmap(vmin));
                atomicMax(&mx_u[row_g], fmap(vmax));
            }
        }
    }

    // packed bf16 store of the sim tile (16 x 16B per lane, coalesced)
    ushort_t* sp = simbuf + (((size_t)(tile_i * NTILE + tile_j) * 512 + tid) * 128);
#pragma unroll
    for (int c = 0; c < 16; c++) {
        int m = c >> 1, n0 = (c & 1) * 2;
        ushort8 o;
        o[0] = f2bf(acc[m][n0][0]);     o[1] = f2bf(acc[m][n0][1]);
        o[2] = f2bf(acc[m][n0][2]);     o[3] = f2bf(acc[m][n0][3]);
        o[4] = f2bf(acc[m][n0 + 1][0]); o[5] = f2bf(acc[m][n0 + 1][1]);
        o[6] = f2bf(acc[m][n0 + 1][2]); o[7] = f2bf(acc[m][n0 + 1][3]);
        reinterpret_cast<ushort8*>(sp)[c] = o;
    }
}

// ---------- kernel 2.5: per-row params {1/img_norm, 1/txt_norm, mn, 1/(mx-mn+eps)} ----------
__global__ __launch_bounds__(256) void params_kernel(
    const float* __restrict__ img_norm, const float* __restrict__ txt_norm,
    const unsigned* __restrict__ mn_u, const unsigned* __restrict__ mx_u,
    float4* __restrict__ params) {
    int i = blockIdx.x * 256 + threadIdx.x;
    float mn = funmap(mn_u[i]), mx = funmap(mx_u[i]);
    params[i] = make_float4(1.0f / img_norm[i], 1.0f / txt_norm[i],
                            mn, 1.0f / (mx - mn + EPS_W));
}

// ---------- kernel 3: dots GEMM + loss; sim front-loaded, params precomputed ----------
__global__ __launch_bounds__(512, 2) void phase2_kernel(
    const ushort_t* __restrict__ Ibf, const ushort_t* __restrict__ Tbf,
    const float4* __restrict__ params, const int* __restrict__ instr,
    const ushort_t* __restrict__ simbuf, float* __restrict__ out) {
    __shared__ __align__(16) ushort_t Ta[2][BT * 64];
    __shared__ __align__(16) ushort_t Tb[2][BT * 64];
    const int tile_j = blockIdx.x, tile_i = blockIdx.y;
    const int tid = threadIdx.x;
    const int wave = tid >> 6, lane = tid & 63;
    const int wr = wave >> 2, wc = wave & 3;
    const ushort_t* gA = Ibf + (size_t)(tile_i * BT) * DIM;
    const ushort_t* gB = Tbf + (size_t)(tile_j * BT) * DIM;

    // T14: front-load the sim readback (written by phase1, complete at launch)
    // so its 32 MB of traffic hides under the K-loop. 64 VGPR held.
    ushort8 sim[16];
    {
        const ushort8* spv = reinterpret_cast<const ushort8*>(
            simbuf + (((size_t)(tile_i * NTILE + tile_j) * 512 + tid) * 128));
#pragma unroll
        for (int c = 0; c < 16; c++) sim[c] = spv[c];
    }

    floatx4 acc[8][4];
#pragma unroll
    for (int m = 0; m < 8; m++)
#pragma unroll
        for (int n = 0; n < 4; n++) acc[m][n] = (floatx4){0.f, 0.f, 0.f, 0.f};

    stage_tile(gA, Ta[0], wave, lane);
    stage_tile(gB, Tb[0], wave, lane);
#pragma unroll
    for (int t = 0; t < NKSTEP; t++) {
        if (t + 1 < NKSTEP) {
            stage_tile(gA + (t + 1) * 64, Ta[(t + 1) & 1], wave, lane);
            stage_tile(gB + (t + 1) * 64, Tb[(t + 1) & 1], wave, lane);
            asm volatile("s_waitcnt vmcnt(8)" ::: "memory");
        } else {
            asm volatile("s_waitcnt vmcnt(0)" ::: "memory");
        }
        __builtin_amdgcn_sched_barrier(0);
        __builtin_amdgcn_s_barrier();
#pragma unroll
        for (int kk = 0; kk < 2; kk++) {
            short8 a[8], b[4];
#pragma unroll
            for (int m = 0; m < 8; m++) a[m] = read_frag(Ta[t & 1], wr * 8 + m, kk, lane);
#pragma unroll
            for (int n = 0; n < 4; n++) b[n] = read_frag(Tb[t & 1], wc * 4 + n, kk, lane);
#pragma unroll
            for (int m = 0; m < 8; m++)
#pragma unroll
                for (int n = 0; n < 4; n++)
                    acc[m][n] = __builtin_amdgcn_mfma_f32_16x16x32_bf16(a[m], b[n], acc[m][n], 0, 0, 0);
        }
        __builtin_amdgcn_sched_barrier(0);
        __builtin_amdgcn_s_barrier();
    }

    // epilogue: per-pair loss. No divides, no funmap; one float4/row.
    const int rbase0 = tile_i * BT + wr * 128;
    const int cbase0 = tile_j * BT + wc * 64;
    float rtn4[4]; int ic4[4];
#pragma unroll
    for (int n = 0; n < 4; n++) {
        int col_g = cbase0 + n * 16 + (lane & 15);
        rtn4[n] = params[col_g].y;
        ic4[n] = instr[col_g];
    }
    float lsum = 0.f;
#pragma unroll
    for (int m = 0; m < 8; m++) {
        ushort8 s0 = sim[m * 2 + 0];
        ushort8 s1 = sim[m * 2 + 1];
        int rb = rbase0 + m * 16 + (lane >> 4) * 4;
#pragma unroll
        for (int reg = 0; reg < 4; reg++) {
            int row_g = rb + reg;
            float4 pp = params[row_g];        // {rinr, rtn, mn, winv}
            int   ir  = instr[row_g];
#pragma unroll
            for (int n = 0; n < 4; n++) {
                int col_g = cbase0 + n * 16 + (lane & 15);
                float simv = (n < 2) ? bf2f(s0[(n & 1) * 4 + reg])
                                     : bf2f(s1[(n & 1) * 4 + reg]);
                float cosv = acc[m][n][reg] * (pp.x * rtn4[n]);
                float w = (simv - pp.z) * pp.w;
                bool aligned = (ir == ic4[n]) || (row_g == col_g);
                lsum += aligned ? (1.0f - cosv) : fmaxf(0.0f, cosv - w);
            }
        }
    }
#pragma unroll
    for (int s = 1; s < 64; s <<= 1) lsum += __shfl_xor(lsum, s);
    if (lane == 0)
        atomicAdd(out, lsum * (1.0f / ((float)NROWS * (float)NROWS)));
}

// ---------- launch ----------
extern "C" void kernel_launch(void* const* d_in, const int* in_sizes, int n_in,
                              void* d_out, int out_size, void* d_ws, size_t ws_size,
                              hipStream_t stream) {
    const float* img = (const float*)d_in[0];
    const float* txt = (const float*)d_in[1];
    const int* instr = (const int*)d_in[2];
    float* out = (float*)d_out;

    char* ws = (char*)d_ws;
    ushort_t* Tbf = (ushort_t*)ws;                                  // 4 MB
    ushort_t* Ibf = (ushort_t*)(ws + (size_t)NROWS * DIM * 2);      // 4 MB
    float* img_norm = (float*)(ws + (size_t)NROWS * DIM * 4);       // 16 KB
    float* txt_norm = img_norm + NROWS;                             // 16 KB
    unsigned* mn_u = (unsigned*)(txt_norm + NROWS);                 // 16 KB
    unsigned* mx_u = mn_u + NROWS;                                  // 16 KB
    float4* params = (float4*)(mx_u + NROWS);                       // 64 KB
    ushort_t* simbuf = (ushort_t*)(params + NROWS);                 // 32 MB

    hipMemsetAsync(d_out, 0, sizeof(float), stream);
    prep_kernel<<<NROWS / 4, 256, 0, stream>>>(img, txt, Ibf, Tbf,
                                               img_norm, txt_norm, mn_u, mx_u);
    dim3 grid(NTILE, NTILE);   // 16 x 16 = 256 blocks = 1 per CU
    phase1_kernel<<<grid, 512, 0, stream>>>(Tbf, mn_u, mx_u, simbuf);
    params_kernel<<<NROWS / 256, 256, 0, stream>>>(img_norm, txt_norm, mn_u, mx_u, params);
    phase2_kernel<<<grid, 512, 0, stream>>>(Ibf, Tbf, params, instr, simbuf, out);
}